// Round 15
// baseline (126.484 us; speedup 1.0000x reference)
//
#include <hip/hip_runtime.h>
#include <math.h>

#define T_ 32
#define B_ 16
#define V_ 30000
#define V4 7500
#define D_ 300
#define DQKV_ 150
#define K_ 10
#define G_ 32
#define N_ 320                // K*G
#define S_ 25000
#define S4 6250
#define SLICE 3125            // S/8: SC row-range per XCD (3.75 MB = one L2)
#define QKP 304               // qk ws row stride (300 -> 304, 16B aligned)
#define NTS 1024              // scan threads
#define NTG 256               // gather threads
#define NTF 384               // finalize threads
#define LCAP 4096             // candidate list capacity (expect ~680 for N(0,1))
#define UTH 0xC0000000u       // u-map(2.0f): accept x >= 2.0

__device__ __forceinline__ unsigned umap(float f) {
    unsigned b = __float_as_uint(f);
    unsigned mask = (unsigned)(((int)b) >> 31);      // 0xFFFFFFFF if negative
    return b ^ (mask | 0x80000000u);                 // ascending uint == ascending float
}
__device__ __forceinline__ bool better_u(unsigned au, int ai, unsigned bu, int bi) {
    return (au > bu) || (au == bu && ai < bi);       // higher val, ties -> lower idx
}

// == Kernel 1: fill + threshold-collect + top-10 + nidx + q + qk -> ws ========
__global__ __launch_bounds__(NTS, 2) void scan_prep_kernel(
    const float* __restrict__ pred, const float* __restrict__ lc,
    const float* __restrict__ Wq, const float* __restrict__ Wk,
    const int* __restrict__ nbt,
    float* __restrict__ out, float* __restrict__ qkws, int* __restrict__ nidxws)
{
    const int row = blockIdx.x, tid = threadIdx.x;
    const int lane = tid & 63, wave = tid >> 6;
    __shared__ unsigned lu[LCAP];          // 16 KB candidate u-keys
    __shared__ int      li[LCAP];          // 16 KB candidate indices
    __shared__ int      cnt;
    __shared__ int      topg[K_];
    __shared__ __align__(16) float lcs[D_];
    __shared__ float    qpart[4][DQKV_];

    if (tid == 0) cnt = 0;
    __syncthreads();

    // fill output row with log(1e-8)
    const float FILL = -18.420680743952367f;
    {
        float4 f4 = make_float4(FILL, FILL, FILL, FILL);
        float4* o4 = (float4*)(out + (size_t)row * S_);
        #pragma unroll
        for (int k = 0; k < 7; ++k) { int i = tid + k * NTS; if (i < S4) o4[i] = f4; }
    }

    // stream row: collect candidates with x >= 2.0 (u >= UTH)
    {
        const float4* p4 = (const float4*)(pred + (size_t)row * V_);
        #pragma unroll
        for (int k = 0; k < 8; ++k) {
            int i = tid + k * NTS;
            if (i < V4) {
                float4 v = p4[i];
                unsigned u0 = umap(v.x), u1 = umap(v.y), u2 = umap(v.z), u3 = umap(v.w);
                int base = i * 4;
                if (u0 >= UTH) { int p = atomicAdd(&cnt, 1); if (p < LCAP) { lu[p] = u0; li[p] = base; } }
                if (u1 >= UTH) { int p = atomicAdd(&cnt, 1); if (p < LCAP) { lu[p] = u1; li[p] = base + 1; } }
                if (u2 >= UTH) { int p = atomicAdd(&cnt, 1); if (p < LCAP) { lu[p] = u2; li[p] = base + 2; } }
                if (u3 >= UTH) { int p = atomicAdd(&cnt, 1); if (p < LCAP) { lu[p] = u3; li[p] = base + 3; } }
            }
        }
    }
    __syncthreads();
    const int c = cnt;

    if (c >= K_ && c <= LCAP) {
        if (wave == 0) {                   // exact top-10 from c candidates
            for (int p = 0; p < K_; ++p) {
                unsigned bu = 0; int bi = 0x7fffffff;
                for (int s = lane; s < c; s += 64) {
                    unsigned uu = lu[s]; int ii = li[s];
                    if (better_u(uu, ii, bu, bi)) { bu = uu; bi = ii; }
                }
                #pragma unroll
                for (int off = 32; off; off >>= 1) {
                    unsigned ou = __shfl_xor(bu, off, 64);
                    int      oi = __shfl_xor(bi, off, 64);
                    if (better_u(ou, oi, bu, bi)) { bu = ou; bi = oi; }
                }
                if (lane == 0) topg[p] = bi;
                for (int s = lane; s < c; s += 64)
                    if (li[s] == bi && lu[s] == bu) lu[s] = 0;
            }
        }
    } else {
        if (wave == 0) {                   // exact fallback: re-scan row
            unsigned tu[K_]; int tix[K_];
            #pragma unroll
            for (int s = 0; s < K_; ++s) { tu[s] = 0; tix[s] = 0x7fffffff; }
            const float* prow = pred + (size_t)row * V_;
            for (int i = lane; i < V_; i += 64) {
                unsigned u = umap(prow[i]);
                if (better_u(u, i, tu[K_-1], tix[K_-1])) {
                    tu[K_-1] = u; tix[K_-1] = i;
                    #pragma unroll
                    for (int s = K_-1; s > 0; --s)
                        if (better_u(tu[s], tix[s], tu[s-1], tix[s-1])) {
                            unsigned a = tu[s]; tu[s] = tu[s-1]; tu[s-1] = a;
                            int b2 = tix[s]; tix[s] = tix[s-1]; tix[s-1] = b2;
                        }
                }
            }
            for (int p = 0; p < K_; ++p) {
                unsigned bu = tu[0]; int bi = tix[0];
                #pragma unroll
                for (int s = 1; s < K_; ++s)
                    if (better_u(tu[s], tix[s], bu, bi)) { bu = tu[s]; bi = tix[s]; }
                #pragma unroll
                for (int off = 32; off; off >>= 1) {
                    unsigned ou = __shfl_xor(bu, off, 64);
                    int      oi = __shfl_xor(bi, off, 64);
                    if (better_u(ou, oi, bu, bi)) { bu = ou; bi = oi; }
                }
                if (lane == 0) topg[p] = bi;
                #pragma unroll
                for (int s = 0; s < K_; ++s)
                    if (tix[s] == bi) tu[s] = 0;
            }
        }
    }
    __syncthreads();

    // nidx gather -> ws  ∥  lcs load (float4)
    if (tid < N_) nidxws[(size_t)row * N_ + tid] = nbt[topg[tid >> 5] * G_ + (tid & 31)];
    if (tid >= 384 && tid < 384 + D_ / 4)
        ((float4*)lcs)[tid - 384] = ((const float4*)(lc + (size_t)row * D_))[tid - 384];
    __syncthreads();

    // q-partials: 600 units, unit=(h*150+j): quarter h of the d-range, col j
    if (tid < 4 * DQKV_) {
        int h = tid / DQKV_;
        int j = tid - h * DQKV_;
        int d0 = h * 75;
        const float* wp = Wq + (size_t)d0 * DQKV_ + j;
        float acc = 0.f;
        #pragma unroll 5
        for (int dd = 0; dd < 75; ++dd)
            acc += lcs[d0 + dd] * wp[(size_t)dd * DQKV_];
        qpart[h][j] = acc;
    }
    __syncthreads();

    // qk[d] = Wk[d,:] . q — wave per d-row (16 waves), coalesced, shfl-reduce
    {
        float qv0 = qpart[0][lane] + qpart[1][lane] + qpart[2][lane] + qpart[3][lane];
        float qv1 = qpart[0][64 + lane] + qpart[1][64 + lane] + qpart[2][64 + lane] + qpart[3][64 + lane];
        float qv2 = (lane < 22) ? (qpart[0][128 + lane] + qpart[1][128 + lane]
                                 + qpart[2][128 + lane] + qpart[3][128 + lane]) : 0.f;
        for (int d = wave; d < D_; d += 16) {
            const float* wr = Wk + (size_t)d * DQKV_;
            float w0 = wr[lane];
            float w1 = wr[64 + lane];
            float w2 = (lane < 22) ? wr[128 + lane] : 0.f;
            float p = w0 * qv0 + w1 * qv1 + w2 * qv2;
            #pragma unroll
            for (int off = 32; off; off >>= 1) p += __shfl_xor(p, off, 64);
            if (lane == 0) qkws[(size_t)row * QKP + d] = p;
        }
    }
}

// == Kernel 2: XCD-local gather. block(row=bid>>3, chunk=bid&7) handles n's ==
//    with nidx in [chunk*3125,(chunk+1)*3125) -> each XCD touches only a
//    3.75 MB SC slice (fits its 4 MB L2). One owner per (row,n): direct write.
__global__ __launch_bounds__(NTG) void gather_kernel(
    const float* __restrict__ SC, const float* __restrict__ qkws,
    const int* __restrict__ nidxws, float* __restrict__ logws)
{
    const int r = blockIdx.x >> 3;
    const int ch = blockIdx.x & 7;
    const int lo = ch * SLICE, hi = lo + SLICE;
    const int tid = threadIdx.x;
    __shared__ int   nid[N_];
    __shared__ __align__(16) float qk[D_];
    __shared__ int   list[N_];
    __shared__ int   lcnt;

    if (tid == 0) lcnt = 0;
    for (int i = tid; i < N_; i += NTG)               // FIX: strided (NTG<N_)
        nid[i] = nidxws[(size_t)r * N_ + i];
    if (tid < D_ / 4)
        ((float4*)qk)[tid] = ((const float4*)(qkws + (size_t)r * QKP))[tid];
    __syncthreads();

    for (int i = tid; i < N_; i += NTG) {             // FIX: strided (NTG<N_)
        int sv = nid[i];
        if (sv >= lo && sv < hi) { int p = atomicAdd(&lcnt, 1); list[p] = i; }
    }
    __syncthreads();
    const int c2 = lcnt;

    // 8 lanes per dot, 9-10 float4 in flight, all reads L2-local
    const float ISC = 0.08164965809277260327f;   // 1/sqrt(150)
    const float4* q4 = (const float4*)qk;
    for (int s = tid; s < 8 * c2; s += NTG) {
        int g = s >> 3, h = s & 7;
        int n = list[g];
        const float4* sc4 = (const float4*)(SC + (size_t)nid[n] * D_);
        int c0 = h * 9;
        float acc = 0.f;
        #pragma unroll
        for (int cc = 0; cc < 9; ++cc) {
            float4 a = sc4[c0 + cc];
            float4 b = q4[c0 + cc];
            acc += a.x * b.x + a.y * b.y + a.z * b.z + a.w * b.w;
        }
        if (h < 3) {
            float4 a = sc4[72 + h];
            float4 b = q4[72 + h];
            acc += a.x * b.x + a.y * b.y + a.z * b.z + a.w * b.w;
        }
        acc += __shfl_xor(acc, 1, 64);
        acc += __shfl_xor(acc, 2, 64);
        acc += __shfl_xor(acc, 4, 64);
        if (h == 0) logws[(size_t)r * N_ + n] = acc * ISC;
    }
}

// == Kernel 3: softmax + last-write-wins dup-kill + scatter ===================
__global__ __launch_bounds__(NTF) void finalize_kernel(
    const float* __restrict__ logws, const int* __restrict__ nidxws,
    float* __restrict__ out)
{
    const int row = blockIdx.x, tid = threadIdx.x;
    const int lane = tid & 63, wave = tid >> 6;
    __shared__ float lg[N_];
    __shared__ int   nid[N_];
    __shared__ int   kills[N_];
    __shared__ float redA[6], redB[6];
    float* outrow = out + (size_t)row * S_;

    if (tid < N_) {
        lg[tid]  = logws[(size_t)row * N_ + tid];
        nid[tid] = nidxws[(size_t)row * N_ + tid];
        kills[tid] = 0;
    }
    __syncthreads();

    float v = (tid < N_) ? lg[tid] : -INFINITY;
    float m = v;
    #pragma unroll
    for (int off = 32; off; off >>= 1) m = fmaxf(m, __shfl_xor(m, off, 64));
    if (lane == 0) redA[wave] = m;
    __syncthreads();
    m = redA[0];
    #pragma unroll
    for (int w = 1; w < 6; ++w) m = fmaxf(m, redA[w]);

    float ss = (tid < N_) ? expf(v - m) : 0.f;
    #pragma unroll
    for (int off = 32; off; off >>= 1) ss += __shfl_xor(ss, off, 64);
    if (lane == 0) redB[wave] = ss;
    __syncthreads();
    float tot = redB[0];
    #pragma unroll
    for (int w = 1; w < 6; ++w) tot += redB[w];
    float lsum = logf(tot);

    for (int s = tid; s < 4 * N_; s += NTF) {
        int n = s >> 2, cix = s & 3;
        int sidx = nid[n];
        int clo = cix * 80;
        int lo2 = (n + 1 > clo) ? n + 1 : clo;
        int hi2 = clo + 80;
        bool mt = false;
        #pragma unroll 4
        for (int n2 = lo2; n2 < hi2; ++n2) mt |= (nid[n2] == sidx);
        if (mt) kills[n] = 1;
    }
    __syncthreads();

    if (tid < N_ && !kills[tid]) outrow[nid[tid]] = (v - m) - lsum;
}

// ================= Fallback: fused single kernel (needs no ws) ===============
#define NWS 16
__device__ __forceinline__ bool better(float av, int ai, float bv, int bi) {
    return (av > bv) || (av == bv && ai < bi);
}
__global__ __launch_bounds__(NTS, 4) void selfatt_fused(
    const float* __restrict__ pred, const float* __restrict__ lc,
    const float* __restrict__ SC, const float* __restrict__ Wq,
    const float* __restrict__ Wk, const int* __restrict__ nbt,
    float* __restrict__ out)
{
    const int row = blockIdx.x, tid = threadIdx.x;
    const int lane = tid & 63, wave = tid >> 6;
    __shared__ float wcv[NWS * K_];
    __shared__ int   wci[NWS * K_];
    __shared__ int   topg[K_];
    __shared__ float lcs[D_];
    __shared__ float qs[DQKV_];
    __shared__ __align__(16) float qks[D_];
    __shared__ int   nidx[N_];
    __shared__ float lg[N_];
    __shared__ int   kills[N_];
    __shared__ float redA[NWS], redB[NWS];
    float* outrow = out + (size_t)row * S_;
    const float FILL = -18.420680743952367f;
    {
        float4 f4 = make_float4(FILL, FILL, FILL, FILL);
        float4* o4 = (float4*)outrow;
        #pragma unroll
        for (int k = 0; k < 7; ++k) { int i = tid + k * NTS; if (i < S4) o4[i] = f4; }
    }
    float tv[K_]; int ti[K_];
    #pragma unroll
    for (int s = 0; s < K_; ++s) { tv[s] = -INFINITY; ti[s] = 0x7fffffff; }
    {
        const float4* p4 = (const float4*)(pred + (size_t)row * V_);
        const float4 NEG = make_float4(-INFINITY, -INFINITY, -INFINITY, -INFINITY);
        float4 a[8]; int ib[8];
        #pragma unroll
        for (int u = 0; u < 8; ++u) {
            int i = tid + u * NTS;
            a[u]  = (i < V4) ? p4[i] : NEG;
            ib[u] = (i < V4) ? i * 4 : 0x7ffffff0;
        }
        #pragma unroll
        for (int u = 0; u < 8; ++u) {
            float x = a[u].x, y = a[u].y, z = a[u].z, w = a[u].w;
            float m4 = fmaxf(fmaxf(x, y), fmaxf(z, w));
            if (!(m4 < tv[K_-1])) {
                float vals[4] = {x, y, z, w};
                #pragma unroll
                for (int cc = 0; cc < 4; ++cc) {
                    float val = vals[cc];
                    int   idx = ib[u] + cc;
                    if (better(val, idx, tv[K_-1], ti[K_-1])) {
                        tv[K_-1] = val; ti[K_-1] = idx;
                        #pragma unroll
                        for (int s = K_-1; s > 0; --s) {
                            if (better(tv[s], ti[s], tv[s-1], ti[s-1])) {
                                float fx = tv[s]; tv[s] = tv[s-1]; tv[s-1] = fx;
                                int   iy = ti[s]; ti[s] = ti[s-1]; ti[s-1] = iy;
                            }
                        }
                    }
                }
            }
        }
    }
    for (int p = 0; p < K_; ++p) {
        float bv = tv[0]; int bi = ti[0];
        #pragma unroll
        for (int s = 1; s < K_; ++s)
            if (better(tv[s], ti[s], bv, bi)) { bv = tv[s]; bi = ti[s]; }
        #pragma unroll
        for (int off = 32; off; off >>= 1) {
            float ov = __shfl_xor(bv, off, 64);
            int   oi = __shfl_xor(bi, off, 64);
            if (better(ov, oi, bv, bi)) { bv = ov; bi = oi; }
        }
        if (lane == 0) { wcv[wave * K_ + p] = bv; wci[wave * K_ + p] = bi; }
        #pragma unroll
        for (int s = 0; s < K_; ++s)
            if (ti[s] == bi) tv[s] = -INFINITY;
    }
    __syncthreads();
    if (wave == 0) {
        float c0v = wcv[lane],      c1v = wcv[64 + lane];
        int   c0i = wci[lane],      c1i = wci[64 + lane];
        float c2v = (lane < 32) ? wcv[128 + lane] : -INFINITY;
        int   c2i = (lane < 32) ? wci[128 + lane] : 0x7fffffff;
        for (int p = 0; p < K_; ++p) {
            float bv = c0v; int bi = c0i;
            if (better(c1v, c1i, bv, bi)) { bv = c1v; bi = c1i; }
            if (better(c2v, c2i, bv, bi)) { bv = c2v; bi = c2i; }
            #pragma unroll
            for (int off = 32; off; off >>= 1) {
                float ov = __shfl_xor(bv, off, 64);
                int   oi = __shfl_xor(bi, off, 64);
                if (better(ov, oi, bv, bi)) { bv = ov; bi = oi; }
            }
            if (lane == 0) topg[p] = bi;
            if (c0i == bi) c0v = -INFINITY;
            if (c1i == bi) c1v = -INFINITY;
            if (c2i == bi) c2v = -INFINITY;
        }
    }
    __syncthreads();
    if (tid < N_) { int g = topg[tid >> 5]; nidx[tid] = nbt[g * G_ + (tid & 31)]; }
    else if (tid < 2 * N_) kills[tid - N_] = 0;
    else if (tid >= 640 && tid < 640 + D_) lcs[tid - 640] = lc[(size_t)row * D_ + (tid - 640)];
    __syncthreads();
    if (tid < 600) {
        int j = tid >> 2, h = tid & 3;
        int d0 = h * 75;
        const float* wp = Wq + (size_t)d0 * DQKV_ + j;
        float acc = 0.f;
        #pragma unroll 5
        for (int dd = 0; dd < 75; ++dd) acc += lcs[d0 + dd] * wp[(size_t)dd * DQKV_];
        acc += __shfl_xor(acc, 1, 64);
        acc += __shfl_xor(acc, 2, 64);
        if (h == 0) qs[j] = acc;
    } else {
        int t0 = tid - 600;
        for (int s = t0; s < 4 * N_; s += 424) {
            int n = s >> 2, cc = s & 3;
            int sidx = nidx[n];
            int clo = cc * 80;
            int lo = (n + 1 > clo) ? n + 1 : clo;
            int hi = clo + 80;
            bool mt = false;
            #pragma unroll 4
            for (int n2 = lo; n2 < hi; ++n2) mt |= (nidx[n2] == sidx);
            if (mt) kills[n] = 1;
        }
    }
    __syncthreads();
    if (tid < 600) {
        int d = tid >> 1, h = tid & 1;
        int j0 = h * 75;
        const float* wrow = Wk + (size_t)d * DQKV_ + j0;
        float acc = 0.f;
        #pragma unroll 5
        for (int jj = 0; jj < 75; ++jj) acc += wrow[jj] * qs[j0 + jj];
        acc += __shfl_xor(acc, 1, 64);
        if (h == 0) qks[d] = acc;
    }
    __syncthreads();
    const float ISC = 0.08164965809277260327f;
    const float4* q4 = (const float4*)qks;
    for (int s = tid; s < 8 * N_; s += NTS) {
        int n = s >> 3, h = s & 7;
        const float4* sc4 = (const float4*)(SC + (size_t)nidx[n] * D_);
        int c0 = h * 9;
        float acc = 0.f;
        #pragma unroll
        for (int cc = 0; cc < 9; ++cc) {
            float4 a = sc4[c0 + cc];
            float4 b = q4[c0 + cc];
            acc += a.x * b.x + a.y * b.y + a.z * b.z + a.w * b.w;
        }
        if (h < 3) {
            float4 a = sc4[72 + h];
            float4 b = q4[72 + h];
            acc += a.x * b.x + a.y * b.y + a.z * b.z + a.w * b.w;
        }
        acc += __shfl_xor(acc, 1, 64);
        acc += __shfl_xor(acc, 2, 64);
        acc += __shfl_xor(acc, 4, 64);
        if (h == 0) lg[n] = acc * ISC;
    }
    __syncthreads();
    float v = (tid < N_) ? lg[tid] : -INFINITY;
    float m = v;
    #pragma unroll
    for (int off = 32; off; off >>= 1) m = fmaxf(m, __shfl_xor(m, off, 64));
    if (lane == 0) redA[wave] = m;
    __syncthreads();
    m = redA[0];
    #pragma unroll
    for (int w = 1; w < NWS; ++w) m = fmaxf(m, redA[w]);
    float e = (tid < N_) ? expf(v - m) : 0.f;
    float ss = e;
    #pragma unroll
    for (int off = 32; off; off >>= 1) ss += __shfl_xor(ss, off, 64);
    if (lane == 0) redB[wave] = ss;
    __syncthreads();
    float tot = redB[0];
    #pragma unroll
    for (int w = 1; w < NWS; ++w) tot += redB[w];
    float lsum = logf(tot);
    if (tid < N_ && !kills[tid]) outrow[nidx[tid]] = (v - m) - lsum;
}

extern "C" void kernel_launch(void* const* d_in, const int* in_sizes, int n_in,
                              void* d_out, int out_size, void* d_ws, size_t ws_size,
                              hipStream_t stream) {
    const float* pred = (const float*)d_in[0];
    const float* lc   = (const float*)d_in[1];
    const float* SC   = (const float*)d_in[2];
    const float* Wq   = (const float*)d_in[3];
    const float* Wk   = (const float*)d_in[4];
    const int*   nbt  = (const int*)d_in[5];
    float* out = (float*)d_out;

    const int nrows = T_ * B_;
    const size_t nQK = (size_t)nrows * QKP;            // floats
    const size_t nNI = (size_t)nrows * N_;             // ints
    const size_t nLG = (size_t)nrows * N_;             // floats
    const size_t need = (nQK + nLG) * sizeof(float) + nNI * sizeof(int);

    if (ws_size >= need) {
        float* qkws   = (float*)d_ws;
        int*   nidxws = (int*)(qkws + nQK);
        float* logws  = (float*)(nidxws + nNI);
        scan_prep_kernel<<<dim3(nrows), dim3(NTS), 0, stream>>>(
            pred, lc, Wq, Wk, nbt, out, qkws, nidxws);
        gather_kernel<<<dim3(nrows * 8), dim3(NTG), 0, stream>>>(
            SC, qkws, nidxws, logws);
        finalize_kernel<<<dim3(nrows), dim3(NTF), 0, stream>>>(
            logws, nidxws, out);
    } else {
        selfatt_fused<<<dim3(T_ * B_), dim3(NTS), 0, stream>>>(
            pred, lc, SC, Wq, Wk, nbt, out);
    }
}

// Round 16
// 110.128 us; speedup vs baseline: 1.1485x; 1.1485x over previous
//
#include <hip/hip_runtime.h>
#include <math.h>

#define T_ 32
#define B_ 16
#define V_ 30000
#define V4 7500
#define D_ 300
#define DQKV_ 150
#define K_ 10
#define G_ 32
#define N_ 320                // K*G
#define S_ 25000
#define S4 6250
#define SLICE 3125            // S/8: SC row-range per XCD (3.75 MB = one L2)
#define QKP 304               // qk ws row stride (300 -> 304, 16B aligned)
#define NTS 1024              // scan threads
#define NTP 512               // prep threads (8 waves)
#define NTG 256               // gather threads
#define NTF 384               // finalize threads
#define LCAP 4096             // candidate list capacity (expect ~680 for N(0,1))
#define UTH 0xC0000000u       // u-map(2.0f): accept x >= 2.0

__device__ __forceinline__ unsigned umap(float f) {
    unsigned b = __float_as_uint(f);
    unsigned mask = (unsigned)(((int)b) >> 31);      // 0xFFFFFFFF if negative
    return b ^ (mask | 0x80000000u);                 // ascending uint == ascending float
}
__device__ __forceinline__ bool better_u(unsigned au, int ai, unsigned bu, int bi) {
    return (au > bu) || (au == bu && ai < bi);       // higher val, ties -> lower idx
}

// ===== Kernel 1: fill + threshold-collect + exact top-10 -> wstop (R13) =====
__global__ __launch_bounds__(NTS, 2) void scan_kernel(
    const float* __restrict__ pred, float* __restrict__ out,
    int* __restrict__ wstop)
{
    const int row = blockIdx.x, tid = threadIdx.x;
    const int lane = tid & 63, wave = tid >> 6;
    __shared__ unsigned lu[LCAP];          // 16 KB candidate u-keys
    __shared__ int      li[LCAP];          // 16 KB candidate indices
    __shared__ int      cnt;

    if (tid == 0) cnt = 0;
    __syncthreads();

    const float FILL = -18.420680743952367f;
    {
        float4 f4 = make_float4(FILL, FILL, FILL, FILL);
        float4* o4 = (float4*)(out + (size_t)row * S_);
        #pragma unroll
        for (int k = 0; k < 7; ++k) { int i = tid + k * NTS; if (i < S4) o4[i] = f4; }
    }

    {
        const float4* p4 = (const float4*)(pred + (size_t)row * V_);
        #pragma unroll
        for (int k = 0; k < 8; ++k) {
            int i = tid + k * NTS;
            if (i < V4) {
                float4 v = p4[i];
                unsigned u0 = umap(v.x), u1 = umap(v.y), u2 = umap(v.z), u3 = umap(v.w);
                int base = i * 4;
                if (u0 >= UTH) { int p = atomicAdd(&cnt, 1); if (p < LCAP) { lu[p] = u0; li[p] = base; } }
                if (u1 >= UTH) { int p = atomicAdd(&cnt, 1); if (p < LCAP) { lu[p] = u1; li[p] = base + 1; } }
                if (u2 >= UTH) { int p = atomicAdd(&cnt, 1); if (p < LCAP) { lu[p] = u2; li[p] = base + 2; } }
                if (u3 >= UTH) { int p = atomicAdd(&cnt, 1); if (p < LCAP) { lu[p] = u3; li[p] = base + 3; } }
            }
        }
    }
    __syncthreads();
    const int c = cnt;

    if (c >= K_ && c <= LCAP) {
        if (wave == 0) {
            for (int p = 0; p < K_; ++p) {
                unsigned bu = 0; int bi = 0x7fffffff;
                for (int s = lane; s < c; s += 64) {
                    unsigned uu = lu[s]; int ii = li[s];
                    if (better_u(uu, ii, bu, bi)) { bu = uu; bi = ii; }
                }
                #pragma unroll
                for (int off = 32; off; off >>= 1) {
                    unsigned ou = __shfl_xor(bu, off, 64);
                    int      oi = __shfl_xor(bi, off, 64);
                    if (better_u(ou, oi, bu, bi)) { bu = ou; bi = oi; }
                }
                if (lane == 0) wstop[row * K_ + p] = bi;
                for (int s = lane; s < c; s += 64)
                    if (li[s] == bi && lu[s] == bu) lu[s] = 0;
            }
        }
    } else {
        if (wave == 0) {                   // exact fallback: re-scan row
            unsigned tu[K_]; int tix[K_];
            #pragma unroll
            for (int s = 0; s < K_; ++s) { tu[s] = 0; tix[s] = 0x7fffffff; }
            const float* prow = pred + (size_t)row * V_;
            for (int i = lane; i < V_; i += 64) {
                unsigned u = umap(prow[i]);
                if (better_u(u, i, tu[K_-1], tix[K_-1])) {
                    tu[K_-1] = u; tix[K_-1] = i;
                    #pragma unroll
                    for (int s = K_-1; s > 0; --s)
                        if (better_u(tu[s], tix[s], tu[s-1], tix[s-1])) {
                            unsigned a = tu[s]; tu[s] = tu[s-1]; tu[s-1] = a;
                            int b2 = tix[s]; tix[s] = tix[s-1]; tix[s-1] = b2;
                        }
                }
            }
            for (int p = 0; p < K_; ++p) {
                unsigned bu = tu[0]; int bi = tix[0];
                #pragma unroll
                for (int s = 1; s < K_; ++s)
                    if (better_u(tu[s], tix[s], bu, bi)) { bu = tu[s]; bi = tix[s]; }
                #pragma unroll
                for (int off = 32; off; off >>= 1) {
                    unsigned ou = __shfl_xor(bu, off, 64);
                    int      oi = __shfl_xor(bi, off, 64);
                    if (better_u(ou, oi, bu, bi)) { bu = ou; bi = oi; }
                }
                if (lane == 0) wstop[row * K_ + p] = bi;
                #pragma unroll
                for (int s = 0; s < K_; ++s)
                    if (tix[s] == bi) tu[s] = 0;
            }
        }
    }
}

// ===== Kernel 2: prep — nidx + q + qk (standalone, 8 waves per row) =========
__global__ __launch_bounds__(NTP, 2) void prep_kernel(
    const float* __restrict__ lc, const float* __restrict__ Wq,
    const float* __restrict__ Wk, const int* __restrict__ nbt,
    const int* __restrict__ wstop,
    float* __restrict__ qkws, int* __restrict__ nidxws)
{
    const int row = blockIdx.x, tid = threadIdx.x;
    const int lane = tid & 63, wave = tid >> 6;
    __shared__ int   topg[K_];
    __shared__ __align__(16) float lcs[D_];
    __shared__ float qpart[2][DQKV_];

    if (tid < K_) topg[tid] = wstop[row * K_ + tid];
    if (tid >= 64 && tid < 64 + D_ / 4)               // lcs as float4
        ((float4*)lcs)[tid - 64] = ((const float4*)(lc + (size_t)row * D_))[tid - 64];
    __syncthreads();

    // nidx -> ws (coalesced 10x128B segments of nbt)
    if (tid < N_) nidxws[(size_t)row * N_ + tid] = nbt[topg[tid >> 5] * G_ + (tid & 31)];

    // q-partials: thread-per-j, d-broadcast from LDS, Wq loads coalesced in j.
    // 300 units: h = d-half (0/1), j = column. 2 accumulators, unroll 10.
    if (tid < 2 * DQKV_) {
        int h = tid / DQKV_;
        int j = tid - h * DQKV_;
        int d0 = h * 150;
        const float* wp = Wq + (size_t)d0 * DQKV_ + j;
        float a0 = 0.f, a1 = 0.f;
        #pragma unroll 5
        for (int dd = 0; dd < 150; dd += 2) {
            a0 += lcs[d0 + dd]     * wp[(size_t)dd * DQKV_];
            a1 += lcs[d0 + dd + 1] * wp[(size_t)(dd + 1) * DQKV_];
        }
        qpart[h][j] = a0 + a1;
    }
    __syncthreads();

    // qk[d] = Wk[d,:] . q — wave per d-row (8 waves), lanes split j (coalesced),
    // shfl-reduce; lane0 stores to qkws.
    {
        float qv0 = qpart[0][lane] + qpart[1][lane];
        float qv1 = qpart[0][64 + lane] + qpart[1][64 + lane];
        float qv2 = (lane < 22) ? (qpart[0][128 + lane] + qpart[1][128 + lane]) : 0.f;
        for (int d = wave; d < D_; d += 8) {
            const float* wr = Wk + (size_t)d * DQKV_;
            float w0 = wr[lane];
            float w1 = wr[64 + lane];
            float w2 = (lane < 22) ? wr[128 + lane] : 0.f;
            float p = w0 * qv0 + w1 * qv1 + w2 * qv2;
            #pragma unroll
            for (int off = 32; off; off >>= 1) p += __shfl_xor(p, off, 64);
            if (lane == 0) qkws[(size_t)row * QKP + d] = p;
        }
    }
}

// == Kernel 3: XCD-local gather. block(row=bid>>3, chunk=bid&7) handles n's ==
__global__ __launch_bounds__(NTG) void gather_kernel(
    const float* __restrict__ SC, const float* __restrict__ qkws,
    const int* __restrict__ nidxws, float* __restrict__ logws)
{
    const int r = blockIdx.x >> 3;
    const int ch = blockIdx.x & 7;
    const int lo = ch * SLICE, hi = lo + SLICE;
    const int tid = threadIdx.x;
    __shared__ int   nid[N_];
    __shared__ __align__(16) float qk[D_];
    __shared__ int   list[N_];
    __shared__ int   lcnt;

    if (tid == 0) lcnt = 0;
    for (int i = tid; i < N_; i += NTG)
        nid[i] = nidxws[(size_t)r * N_ + i];
    if (tid < D_ / 4)
        ((float4*)qk)[tid] = ((const float4*)(qkws + (size_t)r * QKP))[tid];
    __syncthreads();

    for (int i = tid; i < N_; i += NTG) {
        int sv = nid[i];
        if (sv >= lo && sv < hi) { int p = atomicAdd(&lcnt, 1); list[p] = i; }
    }
    __syncthreads();
    const int c2 = lcnt;

    const float ISC = 0.08164965809277260327f;   // 1/sqrt(150)
    const float4* q4 = (const float4*)qk;
    for (int s = tid; s < 8 * c2; s += NTG) {
        int g = s >> 3, h = s & 7;
        int n = list[g];
        const float4* sc4 = (const float4*)(SC + (size_t)nid[n] * D_);
        int c0 = h * 9;
        float acc = 0.f;
        #pragma unroll
        for (int cc = 0; cc < 9; ++cc) {
            float4 a = sc4[c0 + cc];
            float4 b = q4[c0 + cc];
            acc += a.x * b.x + a.y * b.y + a.z * b.z + a.w * b.w;
        }
        if (h < 3) {
            float4 a = sc4[72 + h];
            float4 b = q4[72 + h];
            acc += a.x * b.x + a.y * b.y + a.z * b.z + a.w * b.w;
        }
        acc += __shfl_xor(acc, 1, 64);
        acc += __shfl_xor(acc, 2, 64);
        acc += __shfl_xor(acc, 4, 64);
        if (h == 0) logws[(size_t)r * N_ + n] = acc * ISC;
    }
}

// == Kernel 4: softmax + last-write-wins dup-kill + scatter ===================
__global__ __launch_bounds__(NTF) void finalize_kernel(
    const float* __restrict__ logws, const int* __restrict__ nidxws,
    float* __restrict__ out)
{
    const int row = blockIdx.x, tid = threadIdx.x;
    const int lane = tid & 63, wave = tid >> 6;
    __shared__ float lg[N_];
    __shared__ int   nid[N_];
    __shared__ int   kills[N_];
    __shared__ float redA[6], redB[6];
    float* outrow = out + (size_t)row * S_;

    if (tid < N_) {
        lg[tid]  = logws[(size_t)row * N_ + tid];
        nid[tid] = nidxws[(size_t)row * N_ + tid];
        kills[tid] = 0;
    }
    __syncthreads();

    float v = (tid < N_) ? lg[tid] : -INFINITY;
    float m = v;
    #pragma unroll
    for (int off = 32; off; off >>= 1) m = fmaxf(m, __shfl_xor(m, off, 64));
    if (lane == 0) redA[wave] = m;
    __syncthreads();
    m = redA[0];
    #pragma unroll
    for (int w = 1; w < 6; ++w) m = fmaxf(m, redA[w]);

    float ss = (tid < N_) ? expf(v - m) : 0.f;
    #pragma unroll
    for (int off = 32; off; off >>= 1) ss += __shfl_xor(ss, off, 64);
    if (lane == 0) redB[wave] = ss;
    __syncthreads();
    float tot = redB[0];
    #pragma unroll
    for (int w = 1; w < 6; ++w) tot += redB[w];
    float lsum = logf(tot);

    for (int s = tid; s < 4 * N_; s += NTF) {
        int n = s >> 2, cix = s & 3;
        int sidx = nid[n];
        int clo = cix * 80;
        int lo2 = (n + 1 > clo) ? n + 1 : clo;
        int hi2 = clo + 80;
        bool mt = false;
        #pragma unroll 4
        for (int n2 = lo2; n2 < hi2; ++n2) mt |= (nid[n2] == sidx);
        if (mt) kills[n] = 1;
    }
    __syncthreads();

    if (tid < N_ && !kills[tid]) outrow[nid[tid]] = (v - m) - lsum;
}

// ================= Fallback: fused single kernel (needs no ws) ===============
#define NWS 16
__device__ __forceinline__ bool better(float av, int ai, float bv, int bi) {
    return (av > bv) || (av == bv && ai < bi);
}
__global__ __launch_bounds__(NTS, 4) void selfatt_fused(
    const float* __restrict__ pred, const float* __restrict__ lc,
    const float* __restrict__ SC, const float* __restrict__ Wq,
    const float* __restrict__ Wk, const int* __restrict__ nbt,
    float* __restrict__ out)
{
    const int row = blockIdx.x, tid = threadIdx.x;
    const int lane = tid & 63, wave = tid >> 6;
    __shared__ float wcv[NWS * K_];
    __shared__ int   wci[NWS * K_];
    __shared__ int   topg[K_];
    __shared__ float lcs[D_];
    __shared__ float qs[DQKV_];
    __shared__ __align__(16) float qks[D_];
    __shared__ int   nidx[N_];
    __shared__ float lg[N_];
    __shared__ int   kills[N_];
    __shared__ float redA[NWS], redB[NWS];
    float* outrow = out + (size_t)row * S_;
    const float FILL = -18.420680743952367f;
    {
        float4 f4 = make_float4(FILL, FILL, FILL, FILL);
        float4* o4 = (float4*)outrow;
        #pragma unroll
        for (int k = 0; k < 7; ++k) { int i = tid + k * NTS; if (i < S4) o4[i] = f4; }
    }
    float tv[K_]; int ti[K_];
    #pragma unroll
    for (int s = 0; s < K_; ++s) { tv[s] = -INFINITY; ti[s] = 0x7fffffff; }
    {
        const float4* p4 = (const float4*)(pred + (size_t)row * V_);
        const float4 NEG = make_float4(-INFINITY, -INFINITY, -INFINITY, -INFINITY);
        float4 a[8]; int ib[8];
        #pragma unroll
        for (int u = 0; u < 8; ++u) {
            int i = tid + u * NTS;
            a[u]  = (i < V4) ? p4[i] : NEG;
            ib[u] = (i < V4) ? i * 4 : 0x7ffffff0;
        }
        #pragma unroll
        for (int u = 0; u < 8; ++u) {
            float x = a[u].x, y = a[u].y, z = a[u].z, w = a[u].w;
            float m4 = fmaxf(fmaxf(x, y), fmaxf(z, w));
            if (!(m4 < tv[K_-1])) {
                float vals[4] = {x, y, z, w};
                #pragma unroll
                for (int cc = 0; cc < 4; ++cc) {
                    float val = vals[cc];
                    int   idx = ib[u] + cc;
                    if (better(val, idx, tv[K_-1], ti[K_-1])) {
                        tv[K_-1] = val; ti[K_-1] = idx;
                        #pragma unroll
                        for (int s = K_-1; s > 0; --s) {
                            if (better(tv[s], ti[s], tv[s-1], ti[s-1])) {
                                float fx = tv[s]; tv[s] = tv[s-1]; tv[s-1] = fx;
                                int   iy = ti[s]; ti[s] = ti[s-1]; ti[s-1] = iy;
                            }
                        }
                    }
                }
            }
        }
    }
    for (int p = 0; p < K_; ++p) {
        float bv = tv[0]; int bi = ti[0];
        #pragma unroll
        for (int s = 1; s < K_; ++s)
            if (better(tv[s], ti[s], bv, bi)) { bv = tv[s]; bi = ti[s]; }
        #pragma unroll
        for (int off = 32; off; off >>= 1) {
            float ov = __shfl_xor(bv, off, 64);
            int   oi = __shfl_xor(bi, off, 64);
            if (better(ov, oi, bv, bi)) { bv = ov; bi = oi; }
        }
        if (lane == 0) { wcv[wave * K_ + p] = bv; wci[wave * K_ + p] = bi; }
        #pragma unroll
        for (int s = 0; s < K_; ++s)
            if (ti[s] == bi) tv[s] = -INFINITY;
    }
    __syncthreads();
    if (wave == 0) {
        float c0v = wcv[lane],      c1v = wcv[64 + lane];
        int   c0i = wci[lane],      c1i = wci[64 + lane];
        float c2v = (lane < 32) ? wcv[128 + lane] : -INFINITY;
        int   c2i = (lane < 32) ? wci[128 + lane] : 0x7fffffff;
        for (int p = 0; p < K_; ++p) {
            float bv = c0v; int bi = c0i;
            if (better(c1v, c1i, bv, bi)) { bv = c1v; bi = c1i; }
            if (better(c2v, c2i, bv, bi)) { bv = c2v; bi = c2i; }
            #pragma unroll
            for (int off = 32; off; off >>= 1) {
                float ov = __shfl_xor(bv, off, 64);
                int   oi = __shfl_xor(bi, off, 64);
                if (better(ov, oi, bv, bi)) { bv = ov; bi = oi; }
            }
            if (lane == 0) topg[p] = bi;
            if (c0i == bi) c0v = -INFINITY;
            if (c1i == bi) c1v = -INFINITY;
            if (c2i == bi) c2v = -INFINITY;
        }
    }
    __syncthreads();
    if (tid < N_) { int g = topg[tid >> 5]; nidx[tid] = nbt[g * G_ + (tid & 31)]; }
    else if (tid < 2 * N_) kills[tid - N_] = 0;
    else if (tid >= 640 && tid < 640 + D_) lcs[tid - 640] = lc[(size_t)row * D_ + (tid - 640)];
    __syncthreads();
    if (tid < 600) {
        int j = tid >> 2, h = tid & 3;
        int d0 = h * 75;
        const float* wp = Wq + (size_t)d0 * DQKV_ + j;
        float acc = 0.f;
        #pragma unroll 5
        for (int dd = 0; dd < 75; ++dd) acc += lcs[d0 + dd] * wp[(size_t)dd * DQKV_];
        acc += __shfl_xor(acc, 1, 64);
        acc += __shfl_xor(acc, 2, 64);
        if (h == 0) qs[j] = acc;
    } else {
        int t0 = tid - 600;
        for (int s = t0; s < 4 * N_; s += 424) {
            int n = s >> 2, cc = s & 3;
            int sidx = nidx[n];
            int clo = cc * 80;
            int lo = (n + 1 > clo) ? n + 1 : clo;
            int hi = clo + 80;
            bool mt = false;
            #pragma unroll 4
            for (int n2 = lo; n2 < hi; ++n2) mt |= (nidx[n2] == sidx);
            if (mt) kills[n] = 1;
        }
    }
    __syncthreads();
    if (tid < 600) {
        int d = tid >> 1, h = tid & 1;
        int j0 = h * 75;
        const float* wrow = Wk + (size_t)d * DQKV_ + j0;
        float acc = 0.f;
        #pragma unroll 5
        for (int jj = 0; jj < 75; ++jj) acc += wrow[jj] * qs[j0 + jj];
        acc += __shfl_xor(acc, 1, 64);
        if (h == 0) qks[d] = acc;
    }
    __syncthreads();
    const float ISC = 0.08164965809277260327f;
    const float4* q4 = (const float4*)qks;
    for (int s = tid; s < 8 * N_; s += NTS) {
        int n = s >> 3, h = s & 7;
        const float4* sc4 = (const float4*)(SC + (size_t)nidx[n] * D_);
        int c0 = h * 9;
        float acc = 0.f;
        #pragma unroll
        for (int cc = 0; cc < 9; ++cc) {
            float4 a = sc4[c0 + cc];
            float4 b = q4[c0 + cc];
            acc += a.x * b.x + a.y * b.y + a.z * b.z + a.w * b.w;
        }
        if (h < 3) {
            float4 a = sc4[72 + h];
            float4 b = q4[72 + h];
            acc += a.x * b.x + a.y * b.y + a.z * b.z + a.w * b.w;
        }
        acc += __shfl_xor(acc, 1, 64);
        acc += __shfl_xor(acc, 2, 64);
        acc += __shfl_xor(acc, 4, 64);
        if (h == 0) lg[n] = acc * ISC;
    }
    __syncthreads();
    float v = (tid < N_) ? lg[tid] : -INFINITY;
    float m = v;
    #pragma unroll
    for (int off = 32; off; off >>= 1) m = fmaxf(m, __shfl_xor(m, off, 64));
    if (lane == 0) redA[wave] = m;
    __syncthreads();
    m = redA[0];
    #pragma unroll
    for (int w = 1; w < NWS; ++w) m = fmaxf(m, redA[w]);
    float e = (tid < N_) ? expf(v - m) : 0.f;
    float ss = e;
    #pragma unroll
    for (int off = 32; off; off >>= 1) ss += __shfl_xor(ss, off, 64);
    if (lane == 0) redB[wave] = ss;
    __syncthreads();
    float tot = redB[0];
    #pragma unroll
    for (int w = 1; w < NWS; ++w) tot += redB[w];
    float lsum = logf(tot);
    if (tid < N_ && !kills[tid]) outrow[nidx[tid]] = (v - m) - lsum;
}

extern "C" void kernel_launch(void* const* d_in, const int* in_sizes, int n_in,
                              void* d_out, int out_size, void* d_ws, size_t ws_size,
                              hipStream_t stream) {
    const float* pred = (const float*)d_in[0];
    const float* lc   = (const float*)d_in[1];
    const float* SC   = (const float*)d_in[2];
    const float* Wq   = (const float*)d_in[3];
    const float* Wk   = (const float*)d_in[4];
    const int*   nbt  = (const int*)d_in[5];
    float* out = (float*)d_out;

    const int nrows = T_ * B_;
    const size_t nQK = (size_t)nrows * QKP;            // floats
    const size_t nNI = (size_t)nrows * N_;             // ints
    const size_t nLG = (size_t)nrows * N_;             // floats
    const size_t nTP = (size_t)nrows * K_;             // ints (wstop)
    const size_t need = (nQK + nLG) * sizeof(float) + (nNI + nTP) * sizeof(int);

    if (ws_size >= need) {
        float* qkws   = (float*)d_ws;
        int*   nidxws = (int*)(qkws + nQK);
        float* logws  = (float*)(nidxws + nNI);
        int*   wstop  = (int*)(logws + nLG);
        scan_kernel<<<dim3(nrows), dim3(NTS), 0, stream>>>(pred, out, wstop);
        prep_kernel<<<dim3(nrows), dim3(NTP), 0, stream>>>(
            lc, Wq, Wk, nbt, wstop, qkws, nidxws);
        gather_kernel<<<dim3(nrows * 8), dim3(NTG), 0, stream>>>(
            SC, qkws, nidxws, logws);
        finalize_kernel<<<dim3(nrows), dim3(NTF), 0, stream>>>(
            logws, nidxws, out);
    } else {
        selfatt_fused<<<dim3(T_ * B_), dim3(NTS), 0, stream>>>(
            pred, lc, SC, Wq, Wk, nbt, out);
    }
}

// Round 17
// 101.737 us; speedup vs baseline: 1.2432x; 1.0825x over previous
//
#include <hip/hip_runtime.h>
#include <math.h>

#define T_ 32
#define B_ 16
#define V_ 30000
#define V4 7500
#define D_ 300
#define DQKV_ 150
#define K_ 10
#define G_ 32
#define N_ 320                // K*G
#define S_ 25000
#define S4 6250
#define SLICE 3125            // S/8: SC row-range per XCD (3.75 MB = one L2)
#define QKP 304               // qk ws row stride (300 -> 304, 16B aligned)
#define NTS 1024              // scanqk threads
#define NTG 256               // gather threads
#define NTF 384               // finalize threads
#define LCAP 4096             // candidate list capacity (expect ~680 for N(0,1))
#define UTH 0xC0000000u       // u-map(2.0f): accept x >= 2.0

__device__ __forceinline__ unsigned umap(float f) {
    unsigned b = __float_as_uint(f);
    unsigned mask = (unsigned)(((int)b) >> 31);      // 0xFFFFFFFF if negative
    return b ^ (mask | 0x80000000u);                 // ascending uint == ascending float
}
__device__ __forceinline__ bool better_u(unsigned au, int ai, unsigned bu, int bi) {
    return (au > bu) || (au == bu && ai < bi);       // higher val, ties -> lower idx
}

// == Kernel 1 (block-specialized):
//    blocks [0,512):    fill + threshold-collect + 16-wave parallel top-10 -> wstop
//    blocks [512,1024): q = lc@Wq, qk = Wk@q -> qkws   (independent of scan)
__global__ __launch_bounds__(NTS, 2) void scanqk_kernel(
    const float* __restrict__ pred, const float* __restrict__ lc,
    const float* __restrict__ Wq, const float* __restrict__ Wk,
    float* __restrict__ out, int* __restrict__ wstop, float* __restrict__ qkws)
{
    const int b = blockIdx.x, tid = threadIdx.x;
    const int lane = tid & 63, wave = tid >> 6;
    __shared__ unsigned lu[LCAP];          // 16 KB candidate u-keys
    __shared__ int      li[LCAP];          // 16 KB candidate indices
    __shared__ int      cnt;
    __shared__ unsigned wcv[16 * K_];
    __shared__ int      wci[16 * K_];
    __shared__ __align__(16) float lcs[D_];
    __shared__ float    qpart[2][DQKV_];

    if (b >= T_ * B_) {
        // ---------------- qk path ----------------
        const int row = b - T_ * B_;
        if (tid < D_ / 4)
            ((float4*)lcs)[tid] = ((const float4*)(lc + (size_t)row * D_))[tid];
        __syncthreads();

        // q-partials: thread-per-(half,j); Wq loads coalesced in j
        if (tid < 2 * DQKV_) {
            int h = tid / DQKV_;
            int j = tid - h * DQKV_;
            int d0 = h * 150;
            const float* wp = Wq + (size_t)d0 * DQKV_ + j;
            float a0 = 0.f, a1 = 0.f;
            #pragma unroll 5
            for (int dd = 0; dd < 150; dd += 2) {
                a0 += lcs[d0 + dd]     * wp[(size_t)dd * DQKV_];
                a1 += lcs[d0 + dd + 1] * wp[(size_t)(dd + 1) * DQKV_];
            }
            qpart[h][j] = a0 + a1;
        }
        __syncthreads();

        // qk[d] = Wk[d,:] . q — wave per d-row (16 waves), coalesced + shfl
        float qv0 = qpart[0][lane] + qpart[1][lane];
        float qv1 = qpart[0][64 + lane] + qpart[1][64 + lane];
        float qv2 = (lane < 22) ? (qpart[0][128 + lane] + qpart[1][128 + lane]) : 0.f;
        for (int d = wave; d < D_; d += 16) {
            const float* wr = Wk + (size_t)d * DQKV_;
            float w0 = wr[lane];
            float w1 = wr[64 + lane];
            float w2 = (lane < 22) ? wr[128 + lane] : 0.f;
            float p = w0 * qv0 + w1 * qv1 + w2 * qv2;
            #pragma unroll
            for (int off = 32; off; off >>= 1) p += __shfl_xor(p, off, 64);
            if (lane == 0) qkws[(size_t)row * QKP + d] = p;
        }
        return;
    }

    // ---------------- scan path ----------------
    const int row = b;
    if (tid == 0) cnt = 0;
    __syncthreads();

    const float FILL = -18.420680743952367f;
    {
        float4 f4 = make_float4(FILL, FILL, FILL, FILL);
        float4* o4 = (float4*)(out + (size_t)row * S_);
        #pragma unroll
        for (int k = 0; k < 7; ++k) { int i = tid + k * NTS; if (i < S4) o4[i] = f4; }
    }

    {
        const float4* p4 = (const float4*)(pred + (size_t)row * V_);
        #pragma unroll
        for (int k = 0; k < 8; ++k) {
            int i = tid + k * NTS;
            if (i < V4) {
                float4 v = p4[i];
                unsigned u0 = umap(v.x), u1 = umap(v.y), u2 = umap(v.z), u3 = umap(v.w);
                int base = i * 4;
                if (u0 >= UTH) { int p = atomicAdd(&cnt, 1); if (p < LCAP) { lu[p] = u0; li[p] = base; } }
                if (u1 >= UTH) { int p = atomicAdd(&cnt, 1); if (p < LCAP) { lu[p] = u1; li[p] = base + 1; } }
                if (u2 >= UTH) { int p = atomicAdd(&cnt, 1); if (p < LCAP) { lu[p] = u2; li[p] = base + 2; } }
                if (u3 >= UTH) { int p = atomicAdd(&cnt, 1); if (p < LCAP) { lu[p] = u3; li[p] = base + 3; } }
            }
        }
    }
    __syncthreads();
    const int c = cnt;

    if (c >= K_ && c <= LCAP) {
        // 16-wave parallel select: each wave top-10 of its strided subset
        unsigned cu[4]; int cix[4];
        #pragma unroll
        for (int k = 0; k < 4; ++k) {
            int s = wave * 64 + lane + k * NTS;
            bool ok = s < c;
            cu[k]  = ok ? lu[s] : 0u;
            cix[k] = ok ? li[s] : 0x7fffffff;
        }
        for (int p = 0; p < K_; ++p) {
            unsigned bu = cu[0]; int bi = cix[0];
            #pragma unroll
            for (int k = 1; k < 4; ++k)
                if (better_u(cu[k], cix[k], bu, bi)) { bu = cu[k]; bi = cix[k]; }
            #pragma unroll
            for (int off = 32; off; off >>= 1) {
                unsigned ou = __shfl_xor(bu, off, 64);
                int      oi = __shfl_xor(bi, off, 64);
                if (better_u(ou, oi, bu, bi)) { bu = ou; bi = oi; }
            }
            if (lane == 0) { wcv[wave * K_ + p] = bu; wci[wave * K_ + p] = bi; }
            #pragma unroll
            for (int k = 0; k < 4; ++k)
                if (cix[k] == bi) cu[k] = 0u;
        }
        __syncthreads();

        // wave 0 merges the 160 wave-winners
        if (wave == 0) {
            unsigned c0u = wcv[lane],      c1u = wcv[64 + lane];
            int      c0i = wci[lane],      c1i = wci[64 + lane];
            unsigned c2u = (lane < 32) ? wcv[128 + lane] : 0u;
            int      c2i = (lane < 32) ? wci[128 + lane] : 0x7fffffff;
            for (int p = 0; p < K_; ++p) {
                unsigned bu = c0u; int bi = c0i;
                if (better_u(c1u, c1i, bu, bi)) { bu = c1u; bi = c1i; }
                if (better_u(c2u, c2i, bu, bi)) { bu = c2u; bi = c2i; }
                #pragma unroll
                for (int off = 32; off; off >>= 1) {
                    unsigned ou = __shfl_xor(bu, off, 64);
                    int      oi = __shfl_xor(bi, off, 64);
                    if (better_u(ou, oi, bu, bi)) { bu = ou; bi = oi; }
                }
                if (lane == 0) wstop[row * K_ + p] = bi;
                if (c0i == bi) c0u = 0u;
                if (c1i == bi) c1u = 0u;
                if (c2i == bi) c2u = 0u;
            }
        }
    } else {
        // exact fallback (never triggers for N(0,1) input): wave 0 re-scans row
        if (wave == 0) {
            unsigned tu[K_]; int tix[K_];
            #pragma unroll
            for (int s = 0; s < K_; ++s) { tu[s] = 0; tix[s] = 0x7fffffff; }
            const float* prow = pred + (size_t)row * V_;
            for (int i = lane; i < V_; i += 64) {
                unsigned u = umap(prow[i]);
                if (better_u(u, i, tu[K_-1], tix[K_-1])) {
                    tu[K_-1] = u; tix[K_-1] = i;
                    #pragma unroll
                    for (int s = K_-1; s > 0; --s)
                        if (better_u(tu[s], tix[s], tu[s-1], tix[s-1])) {
                            unsigned a = tu[s]; tu[s] = tu[s-1]; tu[s-1] = a;
                            int b2 = tix[s]; tix[s] = tix[s-1]; tix[s-1] = b2;
                        }
                }
            }
            for (int p = 0; p < K_; ++p) {
                unsigned bu = tu[0]; int bi = tix[0];
                #pragma unroll
                for (int s = 1; s < K_; ++s)
                    if (better_u(tu[s], tix[s], bu, bi)) { bu = tu[s]; bi = tix[s]; }
                #pragma unroll
                for (int off = 32; off; off >>= 1) {
                    unsigned ou = __shfl_xor(bu, off, 64);
                    int      oi = __shfl_xor(bi, off, 64);
                    if (better_u(ou, oi, bu, bi)) { bu = ou; bi = oi; }
                }
                if (lane == 0) wstop[row * K_ + p] = bi;
                #pragma unroll
                for (int s = 0; s < K_; ++s)
                    if (tix[s] == bi) tu[s] = 0;
            }
        }
    }
}

// == Kernel 2: XCD-local gather (computes nidx from wstop+nbt itself) ========
__global__ __launch_bounds__(NTG) void gather_kernel(
    const float* __restrict__ SC, const float* __restrict__ qkws,
    const int* __restrict__ nbt, const int* __restrict__ wstop,
    float* __restrict__ logws)
{
    const int r = blockIdx.x >> 3;
    const int ch = blockIdx.x & 7;
    const int lo = ch * SLICE, hi = lo + SLICE;
    const int tid = threadIdx.x;
    __shared__ int   topg[K_];
    __shared__ int   nid[N_];
    __shared__ __align__(16) float qk[D_];
    __shared__ int   list[N_];
    __shared__ int   lcnt;

    if (tid == 0) lcnt = 0;
    if (tid < K_) topg[tid] = wstop[r * K_ + tid];
    if (tid >= 64 && tid < 64 + D_ / 4)
        ((float4*)qk)[tid - 64] = ((const float4*)(qkws + (size_t)r * QKP))[tid - 64];
    __syncthreads();

    for (int i = tid; i < N_; i += NTG)
        nid[i] = nbt[topg[i >> 5] * G_ + (i & 31)];
    __syncthreads();

    for (int i = tid; i < N_; i += NTG) {
        int sv = nid[i];
        if (sv >= lo && sv < hi) { int p = atomicAdd(&lcnt, 1); list[p] = i; }
    }
    __syncthreads();
    const int c2 = lcnt;

    const float ISC = 0.08164965809277260327f;   // 1/sqrt(150)
    const float4* q4 = (const float4*)qk;
    for (int s = tid; s < 8 * c2; s += NTG) {
        int g = s >> 3, h = s & 7;
        int n = list[g];
        const float4* sc4 = (const float4*)(SC + (size_t)nid[n] * D_);
        int c0 = h * 9;
        float acc = 0.f;
        #pragma unroll
        for (int cc = 0; cc < 9; ++cc) {
            float4 a = sc4[c0 + cc];
            float4 bq = q4[c0 + cc];
            acc += a.x * bq.x + a.y * bq.y + a.z * bq.z + a.w * bq.w;
        }
        if (h < 3) {
            float4 a = sc4[72 + h];
            float4 bq = q4[72 + h];
            acc += a.x * bq.x + a.y * bq.y + a.z * bq.z + a.w * bq.w;
        }
        acc += __shfl_xor(acc, 1, 64);
        acc += __shfl_xor(acc, 2, 64);
        acc += __shfl_xor(acc, 4, 64);
        if (h == 0) logws[(size_t)r * N_ + n] = acc * ISC;
    }
}

// == Kernel 3: softmax + last-write-wins dup-kill + scatter ===================
__global__ __launch_bounds__(NTF) void finalize_kernel(
    const float* __restrict__ logws, const int* __restrict__ nbt,
    const int* __restrict__ wstop, float* __restrict__ out)
{
    const int row = blockIdx.x, tid = threadIdx.x;
    const int lane = tid & 63, wave = tid >> 6;
    __shared__ int   topg[K_];
    __shared__ float lg[N_];
    __shared__ int   nid[N_];
    __shared__ int   kills[N_];
    __shared__ float redA[6], redB[6];
    float* outrow = out + (size_t)row * S_;

    if (tid < K_) topg[tid] = wstop[row * K_ + tid];
    __syncthreads();
    if (tid < N_) {
        nid[tid] = nbt[topg[tid >> 5] * G_ + (tid & 31)];
        lg[tid]  = logws[(size_t)row * N_ + tid];
        kills[tid] = 0;
    }
    __syncthreads();

    float v = (tid < N_) ? lg[tid] : -INFINITY;
    float m = v;
    #pragma unroll
    for (int off = 32; off; off >>= 1) m = fmaxf(m, __shfl_xor(m, off, 64));
    if (lane == 0) redA[wave] = m;
    __syncthreads();
    m = redA[0];
    #pragma unroll
    for (int w = 1; w < 6; ++w) m = fmaxf(m, redA[w]);

    float ss = (tid < N_) ? expf(v - m) : 0.f;
    #pragma unroll
    for (int off = 32; off; off >>= 1) ss += __shfl_xor(ss, off, 64);
    if (lane == 0) redB[wave] = ss;
    __syncthreads();
    float tot = redB[0];
    #pragma unroll
    for (int w = 1; w < 6; ++w) tot += redB[w];
    float lsum = logf(tot);

    for (int s = tid; s < 4 * N_; s += NTF) {
        int n = s >> 2, cix = s & 3;
        int sidx = nid[n];
        int clo = cix * 80;
        int lo2 = (n + 1 > clo) ? n + 1 : clo;
        int hi2 = clo + 80;
        bool mt = false;
        #pragma unroll 4
        for (int n2 = lo2; n2 < hi2; ++n2) mt |= (nid[n2] == sidx);
        if (mt) kills[n] = 1;
    }
    __syncthreads();

    if (tid < N_ && !kills[tid]) outrow[nid[tid]] = (v - m) - lsum;
}

// ================= Fallback: fused single kernel (needs no ws) ===============
#define NWS 16
__device__ __forceinline__ bool better(float av, int ai, float bv, int bi) {
    return (av > bv) || (av == bv && ai < bi);
}
__global__ __launch_bounds__(NTS, 4) void selfatt_fused(
    const float* __restrict__ pred, const float* __restrict__ lc,
    const float* __restrict__ SC, const float* __restrict__ Wq,
    const float* __restrict__ Wk, const int* __restrict__ nbt,
    float* __restrict__ out)
{
    const int row = blockIdx.x, tid = threadIdx.x;
    const int lane = tid & 63, wave = tid >> 6;
    __shared__ float wcv[NWS * K_];
    __shared__ int   wci[NWS * K_];
    __shared__ int   topg[K_];
    __shared__ float lcs[D_];
    __shared__ float qs[DQKV_];
    __shared__ __align__(16) float qks[D_];
    __shared__ int   nidx[N_];
    __shared__ float lg[N_];
    __shared__ int   kills[N_];
    __shared__ float redA[NWS], redB[NWS];
    float* outrow = out + (size_t)row * S_;
    const float FILL = -18.420680743952367f;
    {
        float4 f4 = make_float4(FILL, FILL, FILL, FILL);
        float4* o4 = (float4*)outrow;
        #pragma unroll
        for (int k = 0; k < 7; ++k) { int i = tid + k * NTS; if (i < S4) o4[i] = f4; }
    }
    float tv[K_]; int ti[K_];
    #pragma unroll
    for (int s = 0; s < K_; ++s) { tv[s] = -INFINITY; ti[s] = 0x7fffffff; }
    {
        const float4* p4 = (const float4*)(pred + (size_t)row * V_);
        const float4 NEG = make_float4(-INFINITY, -INFINITY, -INFINITY, -INFINITY);
        float4 a[8]; int ib[8];
        #pragma unroll
        for (int u = 0; u < 8; ++u) {
            int i = tid + u * NTS;
            a[u]  = (i < V4) ? p4[i] : NEG;
            ib[u] = (i < V4) ? i * 4 : 0x7ffffff0;
        }
        #pragma unroll
        for (int u = 0; u < 8; ++u) {
            float x = a[u].x, y = a[u].y, z = a[u].z, w = a[u].w;
            float m4 = fmaxf(fmaxf(x, y), fmaxf(z, w));
            if (!(m4 < tv[K_-1])) {
                float vals[4] = {x, y, z, w};
                #pragma unroll
                for (int cc = 0; cc < 4; ++cc) {
                    float val = vals[cc];
                    int   idx = ib[u] + cc;
                    if (better(val, idx, tv[K_-1], ti[K_-1])) {
                        tv[K_-1] = val; ti[K_-1] = idx;
                        #pragma unroll
                        for (int s = K_-1; s > 0; --s) {
                            if (better(tv[s], ti[s], tv[s-1], ti[s-1])) {
                                float fx = tv[s]; tv[s] = tv[s-1]; tv[s-1] = fx;
                                int   iy = ti[s]; ti[s] = ti[s-1]; ti[s-1] = iy;
                            }
                        }
                    }
                }
            }
        }
    }
    for (int p = 0; p < K_; ++p) {
        float bv = tv[0]; int bi = ti[0];
        #pragma unroll
        for (int s = 1; s < K_; ++s)
            if (better(tv[s], ti[s], bv, bi)) { bv = tv[s]; bi = ti[s]; }
        #pragma unroll
        for (int off = 32; off; off >>= 1) {
            float ov = __shfl_xor(bv, off, 64);
            int   oi = __shfl_xor(bi, off, 64);
            if (better(ov, oi, bv, bi)) { bv = ov; bi = oi; }
        }
        if (lane == 0) { wcv[wave * K_ + p] = bv; wci[wave * K_ + p] = bi; }
        #pragma unroll
        for (int s = 0; s < K_; ++s)
            if (ti[s] == bi) tv[s] = -INFINITY;
    }
    __syncthreads();
    if (wave == 0) {
        float c0v = wcv[lane],      c1v = wcv[64 + lane];
        int   c0i = wci[lane],      c1i = wci[64 + lane];
        float c2v = (lane < 32) ? wcv[128 + lane] : -INFINITY;
        int   c2i = (lane < 32) ? wci[128 + lane] : 0x7fffffff;
        for (int p = 0; p < K_; ++p) {
            float bv = c0v; int bi = c0i;
            if (better(c1v, c1i, bv, bi)) { bv = c1v; bi = c1i; }
            if (better(c2v, c2i, bv, bi)) { bv = c2v; bi = c2i; }
            #pragma unroll
            for (int off = 32; off; off >>= 1) {
                float ov = __shfl_xor(bv, off, 64);
                int   oi = __shfl_xor(bi, off, 64);
                if (better(ov, oi, bv, bi)) { bv = ov; bi = oi; }
            }
            if (lane == 0) topg[p] = bi;
            if (c0i == bi) c0v = -INFINITY;
            if (c1i == bi) c1v = -INFINITY;
            if (c2i == bi) c2v = -INFINITY;
        }
    }
    __syncthreads();
    if (tid < N_) { int g = topg[tid >> 5]; nidx[tid] = nbt[g * G_ + (tid & 31)]; }
    else if (tid < 2 * N_) kills[tid - N_] = 0;
    else if (tid >= 640 && tid < 640 + D_) lcs[tid - 640] = lc[(size_t)row * D_ + (tid - 640)];
    __syncthreads();
    if (tid < 600) {
        int j = tid >> 2, h = tid & 3;
        int d0 = h * 75;
        const float* wp = Wq + (size_t)d0 * DQKV_ + j;
        float acc = 0.f;
        #pragma unroll 5
        for (int dd = 0; dd < 75; ++dd) acc += lcs[d0 + dd] * wp[(size_t)dd * DQKV_];
        acc += __shfl_xor(acc, 1, 64);
        acc += __shfl_xor(acc, 2, 64);
        if (h == 0) qs[j] = acc;
    } else {
        int t0 = tid - 600;
        for (int s = t0; s < 4 * N_; s += 424) {
            int n = s >> 2, cc = s & 3;
            int sidx = nidx[n];
            int clo = cc * 80;
            int lo = (n + 1 > clo) ? n + 1 : clo;
            int hi = clo + 80;
            bool mt = false;
            #pragma unroll 4
            for (int n2 = lo; n2 < hi; ++n2) mt |= (nidx[n2] == sidx);
            if (mt) kills[n] = 1;
        }
    }
    __syncthreads();
    if (tid < 600) {
        int d = tid >> 1, h = tid & 1;
        int j0 = h * 75;
        const float* wrow = Wk + (size_t)d * DQKV_ + j0;
        float acc = 0.f;
        #pragma unroll 5
        for (int jj = 0; jj < 75; ++jj) acc += wrow[jj] * qs[j0 + jj];
        acc += __shfl_xor(acc, 1, 64);
        if (h == 0) qks[d] = acc;
    }
    __syncthreads();
    const float ISC = 0.08164965809277260327f;
    const float4* q4 = (const float4*)qks;
    for (int s = tid; s < 8 * N_; s += NTS) {
        int n = s >> 3, h = s & 7;
        const float4* sc4 = (const float4*)(SC + (size_t)nidx[n] * D_);
        int c0 = h * 9;
        float acc = 0.f;
        #pragma unroll
        for (int cc = 0; cc < 9; ++cc) {
            float4 a = sc4[c0 + cc];
            float4 b = q4[c0 + cc];
            acc += a.x * b.x + a.y * b.y + a.z * b.z + a.w * b.w;
        }
        if (h < 3) {
            float4 a = sc4[72 + h];
            float4 b = q4[72 + h];
            acc += a.x * b.x + a.y * b.y + a.z * b.z + a.w * b.w;
        }
        acc += __shfl_xor(acc, 1, 64);
        acc += __shfl_xor(acc, 2, 64);
        acc += __shfl_xor(acc, 4, 64);
        if (h == 0) lg[n] = acc * ISC;
    }
    __syncthreads();
    float v = (tid < N_) ? lg[tid] : -INFINITY;
    float m = v;
    #pragma unroll
    for (int off = 32; off; off >>= 1) m = fmaxf(m, __shfl_xor(m, off, 64));
    if (lane == 0) redA[wave] = m;
    __syncthreads();
    m = redA[0];
    #pragma unroll
    for (int w = 1; w < NWS; ++w) m = fmaxf(m, redA[w]);
    float e = (tid < N_) ? expf(v - m) : 0.f;
    float ss = e;
    #pragma unroll
    for (int off = 32; off; off >>= 1) ss += __shfl_xor(ss, off, 64);
    if (lane == 0) redB[wave] = ss;
    __syncthreads();
    float tot = redB[0];
    #pragma unroll
    for (int w = 1; w < NWS; ++w) tot += redB[w];
    float lsum = logf(tot);
    if (tid < N_ && !kills[tid]) outrow[nidx[tid]] = (v - m) - lsum;
}

extern "C" void kernel_launch(void* const* d_in, const int* in_sizes, int n_in,
                              void* d_out, int out_size, void* d_ws, size_t ws_size,
                              hipStream_t stream) {
    const float* pred = (const float*)d_in[0];
    const float* lc   = (const float*)d_in[1];
    const float* SC   = (const float*)d_in[2];
    const float* Wq   = (const float*)d_in[3];
    const float* Wk   = (const float*)d_in[4];
    const int*   nbt  = (const int*)d_in[5];
    float* out = (float*)d_out;

    const int nrows = T_ * B_;
    const size_t nQK = (size_t)nrows * QKP;            // floats
    const size_t nLG = (size_t)nrows * N_;             // floats
    const size_t nTP = (size_t)nrows * K_;             // ints (wstop)
    const size_t need = (nQK + nLG) * sizeof(float) + nTP * sizeof(int);

    if (ws_size >= need) {
        float* qkws  = (float*)d_ws;
        float* logws = qkws + nQK;
        int*   wstop = (int*)(logws + nLG);
        scanqk_kernel<<<dim3(nrows * 2), dim3(NTS), 0, stream>>>(
            pred, lc, Wq, Wk, out, wstop, qkws);
        gather_kernel<<<dim3(nrows * 8), dim3(NTG), 0, stream>>>(
            SC, qkws, nbt, wstop, logws);
        finalize_kernel<<<dim3(nrows), dim3(NTF), 0, stream>>>(
            logws, nbt, wstop, out);
    } else {
        selfatt_fused<<<dim3(T_ * B_), dim3(NTS), 0, stream>>>(
            pred, lc, SC, Wq, Wk, nbt, out);
    }
}